// Round 2
// baseline (1175.016 us; speedup 1.0000x reference)
//
#include <hip/hip_runtime.h>
#include <hip/hip_bf16.h>

// QuantizedLinear: out[b,s,o] = sum_i x[b,s,i] * (code[q[o,i]] * absmax[o]) + bias[o]
// M = 4096, K = 4096, N = 16384. absmax index == o because in_features == BLOCK.
//
// R2: (1) XOR bank-swizzle on LDS k-slots (8-way -> 2-way conflicts),
//     (2) XCD-aware 1D block swizzle (B tile L2-resident per XCD),
//     (3) dequant via per-row LDS bf16 table (kills per-elem mul/cvt/global-gather).

typedef __bf16 bf16x8 __attribute__((ext_vector_type(8)));
typedef __bf16 bf16x4 __attribute__((ext_vector_type(4)));
typedef float  f32x4  __attribute__((ext_vector_type(4)));

#define GLD_LDS(gp, lp) \
    __builtin_amdgcn_global_load_lds((const __attribute__((address_space(1))) void*)(gp), \
                                     (__attribute__((address_space(3))) void*)(lp), 16, 0, 0)

static constexpr int M = 4096;
static constexpr int N = 16384;
static constexpr int K = 4096;
static constexpr int BM = 128;
static constexpr int BN = 128;
static constexpr int BK = 32;

// ---------------------------------------------------------------- dequant W
// One block per output row o. Build scaled bf16 table in LDS, then gather.
__global__ __launch_bounds__(256) void dequant_w_lds(const int4* __restrict__ q4,
                                                     const float* __restrict__ code,
                                                     const float* __restrict__ absmax,
                                                     uint2* __restrict__ W)
{
    __shared__ unsigned short tab[256];
    const int o = blockIdx.x;
    const int t = threadIdx.x;
    const float am = absmax[o];
    {
        __bf16 h = (__bf16)(code[t] * am);
        tab[t] = __builtin_bit_cast(unsigned short, h);
    }
    __syncthreads();

    const int4* row = q4 + (size_t)o * (K / 4);
    uint2*      out = W  + (size_t)o * (K / 4);
#pragma unroll
    for (int i = 0; i < 4; ++i) {                 // 4 int4s/thread = 16 elems
        const int idx = i * 256 + t;
        int4 qv = row[idx];
        unsigned lo = (unsigned)tab[qv.x] | ((unsigned)tab[qv.y] << 16);
        unsigned hi = (unsigned)tab[qv.z] | ((unsigned)tab[qv.w] << 16);
        out[idx] = make_uint2(lo, hi);
    }
}

// ---------------------------------------------------------------- x fp32 -> bf16
__global__ __launch_bounds__(256) void cvt_x(const float4* __restrict__ x,
                                             bf16x8* __restrict__ xb)
{
    unsigned gid = blockIdx.x * 256u + threadIdx.x;   // 2M threads, 8 elems each
    float4 a = x[gid * 2];
    float4 b = x[gid * 2 + 1];
    bf16x8 o;
    o[0] = (__bf16)a.x; o[1] = (__bf16)a.y; o[2] = (__bf16)a.z; o[3] = (__bf16)a.w;
    o[4] = (__bf16)b.x; o[5] = (__bf16)b.y; o[6] = (__bf16)b.z; o[7] = (__bf16)b.w;
    xb[gid] = o;
}

// ---------------------------------------------------------------- GEMM C = A @ B^T + bias
// A: M x K bf16 row-major. B: N x K bf16 row-major (= W). C: M x N fp32.
// 256 threads = 4 waves (2x2), each wave owns 64x64 (4x4 of 16x16x32 MFMA).
// LDS layout: logical (row r, 16B k-group g) lives at byte r*64 + (g ^ ((r>>1)&3))*16.
// 2-way max bank aliasing on the b128 fragment reads (free on gfx950).
__global__ __launch_bounds__(256) void gemm_bt_bias(const __bf16* __restrict__ A,
                                                    const __bf16* __restrict__ B,
                                                    const float* __restrict__ bias,
                                                    float* __restrict__ C)
{
    __shared__ __bf16 As[BM * BK];   // 8 KB
    __shared__ __bf16 Bs[BN * BK];   // 8 KB

    const int tid  = threadIdx.x;
    const int lane = tid & 63;
    const int wave = tid >> 6;

    // XCD-aware supertile swizzle: 128-block groups = 8 bn-tiles x 16 bm-tiles.
    // Round-robin block->XCD => each XCD holds ONE B tile (1MB, L2-resident)
    // while sweeping 16 A tiles.
    const int id = blockIdx.x;
    const int g  = id >> 7;           // 32 groups
    const int r  = id & 127;
    const int gx = g & 15;            // 16 groups along bn (128 bn tiles)
    const int gy = g >> 4;            // 2 groups along bm  (32 bm tiles)
    const int bn = (gx * 8  + (r & 7)) * BN;
    const int bm = (gy * 16 + (r >> 3)) * BM;

    const int wm = (wave >> 1) * 64;
    const int wn = (wave & 1) * 64;

    // staging: thread t -> LDS bytes [t*16, t*16+16); logical row = t>>2,
    // k-slot = (t&3) ^ ((row>>1)&3)  (XOR swizzle; rows 64.. keep same form
    // since 64 == 0 mod 4 under >>1&3).
    const int srow  = tid >> 2;
    const int skcol = (((tid & 3) ^ ((srow >> 1) & 3))) * 8;

    const __bf16* ag0 = A + (long long)(bm + srow) * K + skcol;
    const __bf16* bg0 = B + (long long)(bn + srow) * K + skcol;

    f32x4 acc[4][4] = {};

    const int fr = lane & 15;                       // fragment row within 16
    const int fq = lane >> 4;                       // logical k-group 0..3
    const int fs = (fq ^ ((fr >> 1) & 3)) * 8;      // swizzled elem offset in BK

    for (int k0 = 0; k0 < K; k0 += BK) {
        __syncthreads();
        GLD_LDS(ag0 + k0,            As + tid * 8);
        GLD_LDS(ag0 + k0 + 64 * K,   As + 2048 + tid * 8);
        GLD_LDS(bg0 + k0,            Bs + tid * 8);
        GLD_LDS(bg0 + k0 + 64 * K,   Bs + 2048 + tid * 8);
        __syncthreads();

        bf16x8 af[4], bfr[4];
#pragma unroll
        for (int i = 0; i < 4; ++i)
            af[i] = *(const bf16x8*)(As + (wm + i * 16 + fr) * BK + fs);
#pragma unroll
        for (int i = 0; i < 4; ++i)
            bfr[i] = *(const bf16x8*)(Bs + (wn + i * 16 + fr) * BK + fs);

#pragma unroll
        for (int mi = 0; mi < 4; ++mi)
#pragma unroll
            for (int ni = 0; ni < 4; ++ni)
                acc[mi][ni] = __builtin_amdgcn_mfma_f32_16x16x32_bf16(
                    af[mi], bfr[ni], acc[mi][ni], 0, 0, 0);
    }

    // epilogue: D[m=(lane>>4)*4+reg][n=lane&15]
    const int cn = lane & 15;
    const int rq = (lane >> 4) * 4;
#pragma unroll
    for (int ni = 0; ni < 4; ++ni) {
        const int n = bn + wn + ni * 16 + cn;
        const float bv = bias[n];
#pragma unroll
        for (int mi = 0; mi < 4; ++mi) {
#pragma unroll
            for (int rr = 0; rr < 4; ++rr) {
                const int m = bm + wm + mi * 16 + rq + rr;
                C[(long long)m * N + n] = acc[mi][ni][rr] + bv;
            }
        }
    }
}

extern "C" void kernel_launch(void* const* d_in, const int* in_sizes, int n_in,
                              void* d_out, int out_size, void* d_ws, size_t ws_size,
                              hipStream_t stream)
{
    const float* x      = (const float*)d_in[0];   // 2*2048*4096 fp32
    const int*   qw     = (const int*)d_in[1];     // 16384*4096 int32
    const float* absmax = (const float*)d_in[2];   // 16384 fp32
    const float* code   = (const float*)d_in[3];   // 256 fp32
    const float* bias   = (const float*)d_in[4];   // 16384 fp32
    float* out = (float*)d_out;                    // 4096 x 16384 fp32

    __bf16* Wb = (__bf16*)d_ws;                                     // 128 MB
    __bf16* Xb = (__bf16*)((char*)d_ws + (size_t)N * K * sizeof(__bf16)); // 32 MB

    dequant_w_lds<<<N, 256, 0, stream>>>((const int4*)qw, code, absmax, (uint2*)Wb);

    cvt_x<<<(M * (long long)K) / 8 / 256, 256, 0, stream>>>(
        (const float4*)x, (bf16x8*)Xb);

    gemm_bt_bias<<<dim3((M / BM) * (N / BN)), 256, 0, stream>>>(Xb, Wb, bias, out);
}